// Round 8
// baseline (199.283 us; speedup 1.0000x reference)
//
#include <hip/hip_runtime.h>

namespace {

constexpr int K = 32;     // last-axis length
constexpr int RPW = 64;   // rows per wave (= wavefront size)
constexpr int WPB = 2;    // waves per block
constexpr int THREADS = WPB * 64;
constexpr int TF4 = RPW * K / 4;  // 512 float4 per tile

typedef const float4 __attribute__((address_space(1))) gcf4;
typedef float4 __attribute__((address_space(3))) lf4;
typedef float __attribute__((ext_vector_type(4))) f32x4;

// Full streaming cache policy (gfx950 CPol: SC0=1, NT=2, SC1=16 -> 19):
// both HBM streams are touch-once; sc0|sc1|nt takes L2 out of the path
// entirely (no allocate on read, no dirty-victim writeback churn on write).
// AMD's MI300-series STREAM tuning uses exactly this policy.
constexpr int AUX_STREAM = 19;

// Double-buffered sparsemax: HBM->LDS DMA prefetch of tile t+1 overlaps the
// sort/tau compute of tile t. Per-wave buffers, no __syncthreads anywhere.
// LDS layout: slot(r,v) = r*8 + (v ^ (r&7)) -- conflict-free b128 on both
// row-reads and strided re-reads; swizzle applied on the global SRC address
// (global_load_lds writes linearly: slot = i*64 + lane).
__global__ __launch_bounds__(THREADS)
void sparsemax_kernel(const float* __restrict__ x, float* __restrict__ out,
                      int ntiles) {
  __shared__ float4 lds[WPB][2][TF4];  // 2 waves x 2 bufs x 8 KiB = 32 KiB

  const int tid  = threadIdx.x;
  const int widx = tid >> 6;
  const int l    = tid & 63;
  const int a = l >> 3;                    // 0..7
  const int b = l & 7;                     // 0..7
  const int swz    = (l & 0x38) | (b ^ a); // swizzled per-lane src f4 offset
  const int wslot0 = a * 8 + (b ^ a);      // phase-3 slot, i=0
  const int rbase  = l * 8;                // phase-2 row base

  int t = blockIdx.x * WPB + widx;
  const int wstride = gridDim.x * WPB;
  if (t >= ntiles) return;
  int cur = 0;

  // Prologue: DMA tile t into buffer 0, drain.
  {
    const float4* gp = reinterpret_cast<const float4*>(x) + (size_t)t * TF4 + swz;
    float4* lp = &lds[widx][0][0];
#pragma unroll
    for (int i = 0; i < 8; ++i) {
      __builtin_amdgcn_global_load_lds((gcf4*)(gp + i * 64), (lf4*)(lp + i * 64),
                                       16, 0, AUX_STREAM);
    }
  }
  asm volatile("s_waitcnt vmcnt(0)" ::: "memory");
  __builtin_amdgcn_sched_barrier(0);

  for (; t < ntiles; t += wstride) {
    const int tn = t + wstride;
    const bool has_next = (tn < ntiles);

    // Issue next tile's DMA into the other buffer (in flight during compute).
    if (has_next) {
      const float4* gp =
          reinterpret_cast<const float4*>(x) + (size_t)tn * TF4 + swz;
      float4* lp = &lds[widx][cur ^ 1][0];
#pragma unroll
      for (int i = 0; i < 8; ++i) {
        __builtin_amdgcn_global_load_lds((gcf4*)(gp + i * 64),
                                         (lf4*)(lp + i * 64), 16, 0,
                                         AUX_STREAM);
      }
    }

    const float4* __restrict__ wl = &lds[widx][cur][0];

    // Phase 2: lane l gathers row l (8x ds_read_b128, 2 lanes/bank-quad).
    float rr[K];
#pragma unroll
    for (int v = 0; v < 8; ++v) {
      const float4 q = wl[rbase + (v ^ b)];
      rr[4 * v + 0] = q.x;
      rr[4 * v + 1] = q.y;
      rr[4 * v + 2] = q.z;
      rr[4 * v + 3] = q.w;
    }

    // Bitonic sort, descending; 240 compare-exchanges, static indices.
#pragma unroll
    for (int kk = 2; kk <= K; kk <<= 1) {
#pragma unroll
      for (int j = kk >> 1; j > 0; j >>= 1) {
#pragma unroll
        for (int i = 0; i < K; ++i) {
          const int m = i ^ j;
          if (m > i) {
            const float p = rr[i], q = rr[m];
            const float mn = fminf(p, q);
            const float mx = fmaxf(p, q);
            if ((i & kk) == 0) { rr[i] = mx; rr[m] = mn; }
            else               { rr[i] = mn; rr[m] = mx; }
          }
        }
      }
    }

    // cumsum + support count: kz = #{ j : 1 + (j+1)*z_j - cumsum_j > 0 }.
    float csum = 0.0f;
    int kz = 0;
#pragma unroll
    for (int j = 0; j < K; ++j) {
      csum += rr[j];
      const float cond = 1.0f + (float)(j + 1) * rr[j] - csum;
      kz += (cond > 0.0f) ? 1 : 0;
      rr[j] = csum;  // rr now holds cumsum
    }

    // Gather cumsum[kz-1] with a static cndmask chain.
    float csel = rr[K - 1];
#pragma unroll
    for (int j = 0; j < K; ++j) csel = (kz == j + 1) ? rr[j] : csel;

    const float tau = (csel - 1.0f) / (float)kz;

    // Phase 3: re-read originals, apply cross-lane tau, fully-streaming
    // coalesced stores (sc0 sc1 nt).
    f32x4* __restrict__ op =
        reinterpret_cast<f32x4*>(out) + (size_t)t * TF4 + l;
#pragma unroll
    for (int i = 0; i < 8; ++i) {
      const float taur = __shfl(tau, 8 * i + a);
      const float4 q = wl[wslot0 + i * 64];
      f32x4 o;
      o.x = fmaxf(q.x - taur, 0.0f);
      o.y = fmaxf(q.y - taur, 0.0f);
      o.z = fmaxf(q.z - taur, 0.0f);
      o.w = fmaxf(q.w - taur, 0.0f);
      asm volatile("global_store_dwordx4 %0, %1, off sc0 sc1 nt"
                   :: "v"(op + (size_t)i * 64), "v"(o)
                   : "memory");
    }

    // Counted drain: the 8 prefetch loads are the oldest outstanding VMEM
    // ops (issued before this iter's 8 stores; vmcnt retires in order), so
    // vmcnt(8) guarantees the next buffer is resident without draining stores.
    if (has_next) {
      asm volatile("s_waitcnt vmcnt(8)" ::: "memory");
      __builtin_amdgcn_sched_barrier(0);
    }
    cur ^= 1;
  }
}

}  // namespace

extern "C" void kernel_launch(void* const* d_in, const int* in_sizes, int n_in,
                              void* d_out, int out_size, void* d_ws, size_t ws_size,
                              hipStream_t stream) {
  const float* x = (const float*)d_in[0];
  float* out = (float*)d_out;
  const int nrows = in_sizes[0] / K;   // 4,194,304
  const int ntiles = nrows / RPW;      // 65,536

  // 4096 blocks x 2 waves -> 8192 waves, exactly 8 tiles each.
  int blocks = ntiles / (WPB * 8);
  if (blocks < 1) blocks = 1;

  hipLaunchKernelGGL(sparsemax_kernel, dim3(blocks), dim3(THREADS), 0, stream,
                     x, out, ntiles);
}

// Round 9
// 196.164 us; speedup vs baseline: 1.0159x; 1.0159x over previous
//
#include <hip/hip_runtime.h>

namespace {

constexpr int K = 32;     // last-axis length
constexpr int RPW = 64;   // rows per wave (= wavefront size)
constexpr int WPB = 2;    // waves per block
constexpr int THREADS = WPB * 64;
constexpr int TF4 = RPW * K / 4;  // 512 float4 per tile

typedef const float4 __attribute__((address_space(1))) gcf4;
typedef float4 __attribute__((address_space(3))) lf4;
typedef float __attribute__((ext_vector_type(4))) f32x4;

// NT-only cache policy (aux=2): best measured variant (196.4 us, round 7).
// NT avoids L2/L3 allocation + dirty-victim churn for these touch-once
// streams; adding sc0/sc1 scope bits (round 8, aux=19) cost ~1.5% in
// coherence-probe overhead, so we keep NT alone.
constexpr int AUX_NT = 2;

// Double-buffered sparsemax: HBM->LDS DMA prefetch of tile t+1 overlaps the
// sort/tau compute of tile t. Per-wave buffers, no __syncthreads anywhere.
// LDS layout: slot(r,v) = r*8 + (v ^ (r&7)) -- conflict-free b128 on both
// row-reads and strided re-reads; swizzle applied on the global SRC address
// (global_load_lds writes linearly: slot = i*64 + lane).
__global__ __launch_bounds__(THREADS)
void sparsemax_kernel(const float* __restrict__ x, float* __restrict__ out,
                      int ntiles) {
  __shared__ float4 lds[WPB][2][TF4];  // 2 waves x 2 bufs x 8 KiB = 32 KiB

  const int tid  = threadIdx.x;
  const int widx = tid >> 6;
  const int l    = tid & 63;
  const int a = l >> 3;                    // 0..7
  const int b = l & 7;                     // 0..7
  const int swz    = (l & 0x38) | (b ^ a); // swizzled per-lane src f4 offset
  const int wslot0 = a * 8 + (b ^ a);      // phase-3 slot, i=0
  const int rbase  = l * 8;                // phase-2 row base

  int t = blockIdx.x * WPB + widx;
  const int wstride = gridDim.x * WPB;
  if (t >= ntiles) return;
  int cur = 0;

  // Prologue: DMA tile t into buffer 0, drain.
  {
    const float4* gp = reinterpret_cast<const float4*>(x) + (size_t)t * TF4 + swz;
    float4* lp = &lds[widx][0][0];
#pragma unroll
    for (int i = 0; i < 8; ++i) {
      __builtin_amdgcn_global_load_lds((gcf4*)(gp + i * 64), (lf4*)(lp + i * 64),
                                       16, 0, AUX_NT);
    }
  }
  asm volatile("s_waitcnt vmcnt(0)" ::: "memory");
  __builtin_amdgcn_sched_barrier(0);

  for (; t < ntiles; t += wstride) {
    const int tn = t + wstride;
    const bool has_next = (tn < ntiles);

    // Issue next tile's DMA into the other buffer (in flight during compute).
    if (has_next) {
      const float4* gp =
          reinterpret_cast<const float4*>(x) + (size_t)tn * TF4 + swz;
      float4* lp = &lds[widx][cur ^ 1][0];
#pragma unroll
      for (int i = 0; i < 8; ++i) {
        __builtin_amdgcn_global_load_lds((gcf4*)(gp + i * 64),
                                         (lf4*)(lp + i * 64), 16, 0,
                                         AUX_NT);
      }
    }

    const float4* __restrict__ wl = &lds[widx][cur][0];

    // Phase 2: lane l gathers row l (8x ds_read_b128, 2 lanes/bank-quad).
    float rr[K];
#pragma unroll
    for (int v = 0; v < 8; ++v) {
      const float4 q = wl[rbase + (v ^ b)];
      rr[4 * v + 0] = q.x;
      rr[4 * v + 1] = q.y;
      rr[4 * v + 2] = q.z;
      rr[4 * v + 3] = q.w;
    }

    // Bitonic sort, descending; 240 compare-exchanges, static indices.
#pragma unroll
    for (int kk = 2; kk <= K; kk <<= 1) {
#pragma unroll
      for (int j = kk >> 1; j > 0; j >>= 1) {
#pragma unroll
        for (int i = 0; i < K; ++i) {
          const int m = i ^ j;
          if (m > i) {
            const float p = rr[i], q = rr[m];
            const float mn = fminf(p, q);
            const float mx = fmaxf(p, q);
            if ((i & kk) == 0) { rr[i] = mx; rr[m] = mn; }
            else               { rr[i] = mn; rr[m] = mx; }
          }
        }
      }
    }

    // cumsum + support count: kz = #{ j : 1 + (j+1)*z_j - cumsum_j > 0 }.
    float csum = 0.0f;
    int kz = 0;
#pragma unroll
    for (int j = 0; j < K; ++j) {
      csum += rr[j];
      const float cond = 1.0f + (float)(j + 1) * rr[j] - csum;
      kz += (cond > 0.0f) ? 1 : 0;
      rr[j] = csum;  // rr now holds cumsum
    }

    // Gather cumsum[kz-1] with a static cndmask chain.
    float csel = rr[K - 1];
#pragma unroll
    for (int j = 0; j < K; ++j) csel = (kz == j + 1) ? rr[j] : csel;

    const float tau = (csel - 1.0f) / (float)kz;

    // Phase 3: re-read originals, apply cross-lane tau, NT coalesced stores.
    f32x4* __restrict__ op =
        reinterpret_cast<f32x4*>(out) + (size_t)t * TF4 + l;
#pragma unroll
    for (int i = 0; i < 8; ++i) {
      const float taur = __shfl(tau, 8 * i + a);
      const float4 q = wl[wslot0 + i * 64];
      f32x4 o;
      o.x = fmaxf(q.x - taur, 0.0f);
      o.y = fmaxf(q.y - taur, 0.0f);
      o.z = fmaxf(q.z - taur, 0.0f);
      o.w = fmaxf(q.w - taur, 0.0f);
      __builtin_nontemporal_store(o, op + (size_t)i * 64);
    }

    // Counted drain: the 8 prefetch loads are the oldest outstanding VMEM
    // ops (issued before this iter's 8 stores; vmcnt retires in order), so
    // vmcnt(8) guarantees the next buffer is resident without draining stores.
    if (has_next) {
      asm volatile("s_waitcnt vmcnt(8)" ::: "memory");
      __builtin_amdgcn_sched_barrier(0);
    }
    cur ^= 1;
  }
}

}  // namespace

extern "C" void kernel_launch(void* const* d_in, const int* in_sizes, int n_in,
                              void* d_out, int out_size, void* d_ws, size_t ws_size,
                              hipStream_t stream) {
  const float* x = (const float*)d_in[0];
  float* out = (float*)d_out;
  const int nrows = in_sizes[0] / K;   // 4,194,304
  const int ntiles = nrows / RPW;      // 65,536

  // 4096 blocks x 2 waves -> 8192 waves, exactly 8 tiles each.
  int blocks = ntiles / (WPB * 8);
  if (blocks < 1) blocks = 1;

  hipLaunchKernelGGL(sparsemax_kernel, dim3(blocks), dim3(THREADS), 0, stream,
                     x, out, ntiles);
}